// Round 5
// baseline (253.479 us; speedup 1.0000x reference)
//
#include <hip/hip_runtime.h>
#include <cstdint>

// Problem constants: B=4, T=2048, D=1024, H=16, hd=64
#define MFMA16(a, b, c) __builtin_amdgcn_mfma_f32_16x16x32_bf16(a, b, c, 0, 0, 0)
#define MFMA32(a, b, c) __builtin_amdgcn_mfma_f32_32x32x16_bf16(a, b, c, 0, 0, 0)

typedef float  f32x4   __attribute__((ext_vector_type(4)));
typedef float  f32x16  __attribute__((ext_vector_type(16)));
typedef __bf16 bf16x8  __attribute__((ext_vector_type(8)));
typedef short  s16x4   __attribute__((ext_vector_type(4)));
typedef __bf16 bf16x4  __attribute__((ext_vector_type(4)));

// ---- K=8 MFMA for the PV stage: B-fragment (k = 4*cH + j) matches the S-tile
// C-layout rows per lane exactly -> no cross-lane P transform needed at all.
#if __has_builtin(__builtin_amdgcn_mfma_f32_32x32x8bf16_1k)
#define HAVE_MFMA8 1
__device__ __forceinline__ f32x16 MFMA8(uint32_t a0, uint32_t a1,
                                        uint32_t b0, uint32_t b1, f32x16 c) {
  union { uint32_t u[2]; s16x4 v; } ua, ub;
  ua.u[0] = a0; ua.u[1] = a1; ub.u[0] = b0; ub.u[1] = b1;
  return __builtin_amdgcn_mfma_f32_32x32x8bf16_1k(ua.v, ub.v, c, 0, 0, 0);
}
#elif __has_builtin(__builtin_amdgcn_mfma_f32_32x32x8_bf16)
#define HAVE_MFMA8 1
__device__ __forceinline__ f32x16 MFMA8(uint32_t a0, uint32_t a1,
                                        uint32_t b0, uint32_t b1, f32x16 c) {
  union { uint32_t u[2]; bf16x4 v; } ua, ub;
  ua.u[0] = a0; ua.u[1] = a1; ub.u[0] = b0; ub.u[1] = b1;
  return __builtin_amdgcn_mfma_f32_32x32x8_bf16(ua.v, ub.v, c, 0, 0, 0);
}
#else
#define HAVE_MFMA8 0
#endif

__device__ __forceinline__ void gload_lds16(const void* g, const void* l) {
  __builtin_amdgcn_global_load_lds(
      (const __attribute__((address_space(1))) unsigned int*)(uintptr_t)g,
      (__attribute__((address_space(3))) unsigned int*)(unsigned int)(uintptr_t)l,
      16, 0, 0);
}

__device__ __forceinline__ uint32_t pack_bf16(float a, float b) {
  union { __bf16 h[2]; uint32_t u; } u;
  u.h[0] = (__bf16)a; u.h[1] = (__bf16)b;
  return u.u;
}

__device__ __forceinline__ float fexp2(float x) { return __builtin_amdgcn_exp2f(x); }

// ---------------- fp32 -> bf16 convert (vectorized) ----------------
__global__ void k_cvt(const float* __restrict__ in, __bf16* __restrict__ out, int n4) {
  int i = blockIdx.x * 256 + threadIdx.x;
  if (i >= n4) return;
  float4 v = reinterpret_cast<const float4*>(in)[i];
  __bf16 o[4] = {(__bf16)v.x, (__bf16)v.y, (__bf16)v.z, (__bf16)v.w};
  *reinterpret_cast<uint2*>(out + (size_t)i * 4) = *reinterpret_cast<const uint2*>(o);
}

// ---------------- fp32 [R][C] -> bf16 [C][R] tiled transpose ----------------
__global__ void k_transpose(const float* __restrict__ in, __bf16* __restrict__ out,
                            int R, int C) {
  __shared__ float tile[32][33];
  const int c0 = blockIdx.x * 32, r0 = blockIdx.y * 32;
  const int x = threadIdx.x & 31, y = threadIdx.x >> 5;
#pragma unroll
  for (int i = 0; i < 4; ++i)
    tile[y + i * 8][x] = in[(size_t)(r0 + y + i * 8) * C + c0 + x];
  __syncthreads();
#pragma unroll
  for (int i = 0; i < 4; ++i)
    out[(size_t)(c0 + y + i * 8) * R + r0 + x] = (__bf16)tile[x][y + i * 8];
}

// ---------------- GEMM1: qkv = x @ W_attn + b_attn, scattered to Q/K/VT ----
// 256x256 tile, BK=64, 8 waves (2M x 4N), 128 KiB LDS, 8-phase schedule with
// counted vmcnt (T3+T4), XOR LDS swizzle both-sides (T2, rule 21), setprio (T5),
// bijective XCD swizzle (T1).
#define STG_A(kt, h, b)                                                        \
  do {                                                                         \
    gload_lds16(gA0 + (h) * 131072 + (kt) * 64,                                \
                GS + (b) * 32768 + (h) * 16384 + tid * 16);                    \
    gload_lds16(gA0 + (h) * 131072 + 65536 + (kt) * 64,                        \
                GS + (b) * 32768 + (h) * 16384 + 8192 + tid * 16);             \
  } while (0)
#define STG_B(kt, h, b)                                                        \
  do {                                                                         \
    gload_lds16(gB0 + (h) * 131072 + (kt) * 64,                                \
                GS + 65536 + (b) * 32768 + (h) * 16384 + tid * 16);            \
    gload_lds16(gB0 + (h) * 131072 + 65536 + (kt) * 64,                        \
                GS + 65536 + (b) * 32768 + (h) * 16384 + 8192 + tid * 16);     \
  } while (0)

#define WAITV4 __asm__ volatile("s_waitcnt vmcnt(4)" ::: "memory")
#define NOWAIT (void)0

#define PH(mhv, ksv, bufv, READB, STAGE_STMT, TAILWAIT)                        \
  do {                                                                         \
    bf16x8 aF_[4];                                                             \
    const char* Ap_ = GS + (bufv) * 32768 + Abase + (mhv) * 8192;              \
    _Pragma("unroll") for (int i_ = 0; i_ < 4; ++i_)                           \
        aF_[i_] = *(const bf16x8*)(Ap_ + i_ * 2048 + swz[ksv]);                \
    if (READB) {                                                               \
      const char* Bp_ = GS + (bufv) * 32768 + Bbase;                           \
      _Pragma("unroll") for (int n_ = 0; n_ < 4; ++n_)                         \
          bK[ksv][n_] = *(const bf16x8*)(Bp_ + n_ * 2048 + swz[ksv]);          \
    }                                                                          \
    STAGE_STMT;                                                                \
    __builtin_amdgcn_s_barrier();                                              \
    __asm__ volatile("s_waitcnt lgkmcnt(0)" ::: "memory");                     \
    __builtin_amdgcn_s_setprio(1);                                             \
    _Pragma("unroll") for (int i_ = 0; i_ < 4; ++i_)                           \
        _Pragma("unroll") for (int n_ = 0; n_ < 4; ++n_)                       \
            acc[(mhv) * 4 + i_][n_] =                                          \
                MFMA16(aF_[i_], bK[ksv][n_], acc[(mhv) * 4 + i_][n_]);         \
    __builtin_amdgcn_s_setprio(0);                                             \
    TAILWAIT;                                                                  \
    __builtin_amdgcn_s_barrier();                                              \
  } while (0)

__global__ __launch_bounds__(512, 2) void k_gemm_qkv(
    const __bf16* __restrict__ A, const __bf16* __restrict__ Bt,
    const float* __restrict__ bias,
    __bf16* __restrict__ Qg, __bf16* __restrict__ Kg, __bf16* __restrict__ VTg) {
  __shared__ __align__(16) char GS[131072];
  const int tid = threadIdx.x;
  const int w = tid >> 6, l = tid & 63;
  const int l15 = l & 15, quad = l >> 4;
  const int wr = w >> 2, wc = w & 3;           // 2M x 4N wave grid

  // T1 bijective XCD swizzle: HW linear id L (x-fastest) -> XCD = L % 8.
  // XCD c gets rows by in [4c,4c+4), visited y-fastest within the chunk.
  const int Lid = blockIdx.x + 12 * blockIdx.y;   // 384 blocks, 384 % 8 == 0
  const int xcd = Lid & 7;
  const int i48 = Lid >> 3;                       // [0,48)
  const int bx = i48 >> 2;                        // [0,12)
  const int by = (xcd << 2) + (i48 & 3);          // [0,32)
  const int bm0 = by * 256, bn0 = bx * 256;
  const int which = bx >> 2;                      // 0 Q, 1 K, 2 V (block-uniform)
  const float SC = 0.18033688011112042f;

  const int srow = tid >> 3;
  const int scol = ((tid & 7) ^ (srow & 7)) * 8;
  const __bf16* gA0 = A + (size_t)(bm0 + srow) * 1024 + scol;
  const __bf16* gB0 = Bt + (size_t)(bn0 + srow) * 1024 + scol;

  const int Abase = wr * 16384 + l15 * 128;
  const int Bbase = 65536 + (wc >> 1) * 16384 + (wc & 1) * 8192 + l15 * 128;
  int swz[2];
  swz[0] = ((0 + quad) ^ (l15 & 7)) * 16;
  swz[1] = ((4 + quad) ^ (l15 & 7)) * 16;

  f32x4 acc[8][4] = {};
  bf16x8 bK[2][4];

  STG_B(0, 0, 0); STG_B(0, 1, 0);
  STG_A(0, 0, 0); STG_A(0, 1, 0);
  STG_B(1, 0, 1); STG_B(1, 1, 1);
  __asm__ volatile("s_waitcnt vmcnt(4)" ::: "memory");
  __builtin_amdgcn_s_barrier();

#pragma unroll 1
  for (int u = 0; u < 8; ++u) {
    const int kA1 = 2 * u + 1;
    const int kN0 = 2 * u + 2;
    const int kN1 = 2 * u + 3;
    PH(0, 0, 0, true,  STG_A(kA1, 0, 1), NOWAIT);
    PH(0, 1, 0, true,  STG_A(kA1, 1, 1), NOWAIT);
    PH(1, 0, 0, false, STG_B(kN0, 0, 0), NOWAIT);
    PH(1, 1, 0, false, STG_B(kN0, 1, 0), WAITV4);
    PH(0, 0, 1, true,  STG_A(kN0, 0, 0), NOWAIT);
    PH(0, 1, 1, true,  STG_A(kN0, 1, 0), NOWAIT);
    PH(1, 0, 1, false, STG_B(kN1, 0, 1), NOWAIT);
    PH(1, 1, 1, false, STG_B(kN1, 1, 1), WAITV4);
  }

  __asm__ volatile("s_waitcnt vmcnt(0) lgkmcnt(0)" ::: "memory");
  __syncthreads();

  if (which < 2) {
    __bf16* dst = which == 0 ? Qg : Kg;
    const float mul = which == 0 ? SC : 1.0f;
    const int hh = ((bn0 & 1023) >> 6) + wc;
    const int bb = bm0 >> 11;
    const int tt0 = (bm0 & 2047) + wr * 128;
    float bv4[4];
#pragma unroll
    for (int nf = 0; nf < 4; ++nf) bv4[nf] = bias[bn0 + wc * 64 + nf * 16 + l15];
    __bf16* TR = (__bf16*)(GS + w * 2304);
    const int rrow = l >> 2, cc = l & 3;
    __bf16* gbase = dst + ((size_t)(bb * 16 + hh) * 2048 + tt0) * 64;
#pragma unroll
    for (int f = 0; f < 8; ++f) {
#pragma unroll
      for (int nf = 0; nf < 4; ++nf)
#pragma unroll
        for (int r = 0; r < 4; ++r)
          TR[(quad * 4 + r) * 72 + nf * 16 + l15] =
              (__bf16)((acc[f][nf][r] + bv4[nf]) * mul);
      __asm__ volatile("s_waitcnt lgkmcnt(0)" ::: "memory");
      uint4 v0 = *(const uint4*)(TR + rrow * 72 + cc * 8);
      uint4 v1 = *(const uint4*)(TR + rrow * 72 + cc * 8 + 32);
      __bf16* gp = gbase + (size_t)(f * 16 + rrow) * 64 + cc * 8;
      *(uint4*)gp = v0;
      *(uint4*)(gp + 32) = v1;
      __asm__ volatile("" ::: "memory");
    }
  } else {
    const int hv = (bn0 + wc * 64 - 2048) >> 6;
    const int bb = bm0 >> 11;
    float bv4[4];
#pragma unroll
    for (int nf = 0; nf < 4; ++nf) bv4[nf] = bias[bn0 + wc * 64 + nf * 16 + l15];
    __bf16* VL = (__bf16*)(GS + w * 9216);
    const int t0base = (bm0 & 2047) + wr * 128;
    __bf16* vrowb = VTg + (size_t)(bb * 16 + hv) * 64 * 2048;
#pragma unroll
    for (int pg = 0; pg < 2; ++pg) {
#pragma unroll
      for (int fi = 0; fi < 4; ++fi) {
#pragma unroll
        for (int nf = 0; nf < 4; ++nf)
#pragma unroll
          for (int r = 0; r < 4; ++r)
            VL[(nf * 16 + l15) * 72 + fi * 16 + quad * 4 + r] =
                (__bf16)(acc[pg * 4 + fi][nf][r] + bv4[nf]);
      }
      __asm__ volatile("s_waitcnt lgkmcnt(0)" ::: "memory");
      const int c = l & 7;
#pragma unroll
      for (int it = 0; it < 8; ++it) {
        const int dr = (l >> 3) + 8 * it;
        uint4 vv = *(const uint4*)(VL + dr * 72 + c * 8);
        *(uint4*)(vrowb + (size_t)dr * 2048 + t0base + pg * 64 + c * 8) = vv;
      }
      __asm__ volatile("" ::: "memory");
    }
  }
}

// ---------------- Flash attention: single-wave blocks, barrier-free ---------
// Grid (64, 32), 64 threads. Each block = ONE wave owning 64 q-rows (q-tile
// p = balance-map(blockIdx.y)); ~8 blocks/CU (16 KiB LDS single-buffer each).
// Per 64-kv iter: wait stage -> ds_read K/V frags to regs -> lgkm drain ->
// issue NEXT tile's gload_lds (latency hides under compute) -> QK 16xMFMA32,
// fixed-max softmax, PV 32xMFMA8 (packed P dwords ARE the B-fragment).
// No __syncthreads anywhere: stalled waves are covered by co-resident blocks;
// short q-tiles drain and long ones keep ~8-deep CU occupancy.
__global__ __launch_bounds__(64) void k_attn(
    const __bf16* __restrict__ Qg, const __bf16* __restrict__ Kg,
    const __bf16* __restrict__ VTg, __bf16* __restrict__ yb) {
  __shared__ __align__(16) char smem[16384];   // K [64][128B] ; V [64][128B]
  const int l = threadIdx.x;
  const int l31 = l & 31, cH = l >> 5;
  const int bh = blockIdx.x;
  const int bb = bh >> 4, h = bh & 15;

  // balance map: octet {y, y+4, y+8, ...} (conjectured CU co-residents) gets
  // q-tiles summing 132 iters each; bijective over [0,32).
  const int o = blockIdx.y & 3, kq = blockIdx.y >> 2;
  const int base = (kq >> 1) * 4 + o;
  const int p = (kq & 1) ? (31 - base) : base;   // q-tile index, 64 rows

  const __bf16* Qb = Qg + (size_t)bh * 2048 * 64;

  // staging (pre-swizzled global source, linear LDS dest; 8 rounds x 1KB each)
  const int sr = l >> 3;                          // [0,8) row-in-round
  const int sc = ((l & 7) ^ (sr & 7)) * 8;        // swizzled 16B chunk
  const __bf16* gK = Kg + ((size_t)bh * 2048 + sr) * 64 + sc;
  const __bf16* gV = VTg + ((size_t)bh * 64 + sr) * 2048 + sc;
  char* KS = smem;
  char* VS = smem + 8192;

#define STAGE1(jj)                                                             \
  do {                                                                         \
    const size_t ko_ = (size_t)(jj) * 4096;                                    \
    _Pragma("unroll") for (int r_ = 0; r_ < 8; ++r_)                           \
        gload_lds16(gK + ko_ + r_ * 512, KS + r_ * 1024 + l * 16);             \
    const int vo_ = 64 * (jj);                                                 \
    _Pragma("unroll") for (int r_ = 0; r_ < 8; ++r_)                           \
        gload_lds16(gV + vo_ + r_ * 16384, VS + r_ * 1024 + l * 16);           \
  } while (0)

  // lane-constant LDS read offsets (bytes)
  int koffB[2][4];
#pragma unroll
  for (int kvg = 0; kvg < 2; ++kvg)
#pragma unroll
    for (int s = 0; s < 4; ++s)
      koffB[kvg][s] = (kvg * 32 + l31) * 128 + (((2 * s + cH) ^ (l31 & 7)) * 16);
  int voffA[2][4], voffV[2][4];
#pragma unroll
  for (int kvg = 0; kvg < 2; ++kvg)
#pragma unroll
    for (int g = 0; g < 4; ++g) {
      voffA[kvg][g] = l31 * 128 + (((4 * kvg + g) ^ (l31 & 7)) * 16) + 8 * cH;
      voffV[kvg][g] = voffA[kvg][g] + 32 * 128;
    }

  // Q fragments (64 q-rows, 2 groups of 32)
  bf16x8 qf[2][4];
#pragma unroll
  for (int qg = 0; qg < 2; ++qg)
#pragma unroll
    for (int s = 0; s < 4; ++s)
      qf[qg][s] = *(const bf16x8*)(Qb + (size_t)(p * 64 + qg * 32 + l31) * 64 +
                                   s * 16 + cH * 8);

  f32x16 o00 = {}, o01 = {}, o10 = {}, o11 = {};  // o[dg][qg]
  float lsum0 = 0.f, lsum1 = 0.f;

  STAGE1(0);

#pragma unroll 1
  for (int j = 0; j <= p; ++j) {
    const bool diag = (j == p);
    // wait for stage j, read all fragments to regs
    __asm__ volatile("s_waitcnt vmcnt(0)" ::: "memory");
    __builtin_amdgcn_sched_barrier(0);
    bf16x8 kf[2][4];
    uint2 va[2][4], vb[2][4];
#pragma unroll
    for (int kvg = 0; kvg < 2; ++kvg)
#pragma unroll
      for (int s = 0; s < 4; ++s)
        kf[kvg][s] = *(const bf16x8*)(KS + koffB[kvg][s]);
#pragma unroll
    for (int kvg = 0; kvg < 2; ++kvg)
#pragma unroll
      for (int g = 0; g < 4; ++g) {
        va[kvg][g] = *(const uint2*)(VS + voffA[kvg][g]);
        vb[kvg][g] = *(const uint2*)(VS + voffV[kvg][g]);
      }
    // all LDS reads done -> safe to overwrite buffer; issue next stage early
    __asm__ volatile("s_waitcnt lgkmcnt(0)" ::: "memory");
    __builtin_amdgcn_sched_barrier(0);
    if (j < p) STAGE1(j + 1);

    uint32_t pk[2][2][4][2];   // [kvg][qg][rq][half]
#pragma unroll
    for (int kvg = 0; kvg < 2; ++kvg) {
#pragma unroll
      for (int qg = 0; qg < 2; ++qg) {
        if (kvg == 1 && qg == 0 && diag) continue;  // fully-masked quadrant
        f32x16 st = {};
#pragma unroll
        for (int s = 0; s < 4; ++s) st = MFMA32(kf[kvg][s], qf[qg][s], st);
        if (diag && kvg == qg) {
#pragma unroll
          for (int r = 0; r < 16; ++r) {
            const int off = (r & 3) + 8 * (r >> 2) + 4 * cH;
            if (off > l31) st[r] = -1e30f;
          }
        }
        float ppv[16];
#pragma unroll
        for (int r = 0; r < 16; ++r) ppv[r] = fexp2(st[r]);
        float s01 = (ppv[0] + ppv[1]) + (ppv[2] + ppv[3]);
        float s23 = (ppv[4] + ppv[5]) + (ppv[6] + ppv[7]);
        float s45 = (ppv[8] + ppv[9]) + (ppv[10] + ppv[11]);
        float s67 = (ppv[12] + ppv[13]) + (ppv[14] + ppv[15]);
        const float ss = (s01 + s23) + (s45 + s67);
        if (qg == 0) lsum0 += ss; else lsum1 += ss;
#pragma unroll
        for (int rq = 0; rq < 4; ++rq) {
          pk[kvg][qg][rq][0] = pack_bf16(ppv[4 * rq], ppv[4 * rq + 1]);
          pk[kvg][qg][rq][1] = pack_bf16(ppv[4 * rq + 2], ppv[4 * rq + 3]);
        }
      }
    }

#if HAVE_MFMA8
#pragma unroll
    for (int kvg = 0; kvg < 2; ++kvg)
#pragma unroll
      for (int g = 0; g < 4; ++g) {
        o01 = MFMA8(va[kvg][g].x, va[kvg][g].y, pk[kvg][1][g][0], pk[kvg][1][g][1], o01);
        o11 = MFMA8(vb[kvg][g].x, vb[kvg][g].y, pk[kvg][1][g][0], pk[kvg][1][g][1], o11);
        if (!(diag && kvg == 1)) {
          o00 = MFMA8(va[kvg][g].x, va[kvg][g].y, pk[kvg][0][g][0], pk[kvg][0][g][1], o00);
          o10 = MFMA8(vb[kvg][g].x, vb[kvg][g].y, pk[kvg][0][g][0], pk[kvg][0][g][1], o10);
        }
      }
#else
    // fallback: K=16 MFMA with shfl-based B-fragment assembly
#pragma unroll
    for (int kvg = 0; kvg < 2; ++kvg)
#pragma unroll
      for (int s2 = 0; s2 < 2; ++s2)
#pragma unroll
        for (int qg = 0; qg < 2; ++qg) {
          if (qg == 0 && diag && kvg == 1) continue;
          const int rq_own = 2 * s2 + cH;
          const int rq_snd = 2 * s2 + 1 - cH;
          const uint32_t own0 = pk[kvg][qg][rq_own][0];
          const uint32_t own1 = pk[kvg][qg][rq_own][1];
          const uint32_t rcv0 =
              (uint32_t)__shfl_xor((int)pk[kvg][qg][rq_snd][0], 32, 64);
          const uint32_t rcv1 =
              (uint32_t)__shfl_xor((int)pk[kvg][qg][rq_snd][1], 32, 64);
          union { uint32_t u[4]; bf16x8 v; } pf;
          pf.u[0] = cH ? rcv0 : own0;
          pf.u[1] = cH ? rcv1 : own1;
          pf.u[2] = cH ? own0 : rcv0;
          pf.u[3] = cH ? own1 : rcv1;
          union { uint2 u2[2]; bf16x8 v; } vfa, vfb;
          vfa.u2[0] = va[kvg][2 * s2]; vfa.u2[1] = va[kvg][2 * s2 + 1];
          vfb.u2[0] = vb[kvg][2 * s2]; vfb.u2[1] = vb[kvg][2 * s2 + 1];
          if (qg == 0) {
            o00 = MFMA32(vfa.v, pf.v, o00);
            o10 = MFMA32(vfb.v, pf.v, o10);
          } else {
            o01 = MFMA32(vfa.v, pf.v, o01);
            o11 = MFMA32(vfb.v, pf.v, o11);
          }
        }
#endif
  }

  // direct output: this wave owns q-rows [64p, 64p+64)
  const float stot0 = lsum0 + __shfl_xor(lsum0, 32, 64);
  const float stot1 = lsum1 + __shfl_xor(lsum1, 32, 64);
  const float inv0 = 1.0f / stot0;
  const float inv1 = 1.0f / stot1;
  __bf16* yrow0 = yb + ((size_t)(bb * 2048 + p * 64 + l31)) * 1024 + h * 64;
  __bf16* yrow1 = yrow0 + (size_t)32 * 1024;
#pragma unroll
  for (int rq = 0; rq < 4; ++rq) {
    __bf16 ov[4];
#pragma unroll
    for (int i = 0; i < 4; ++i) ov[i] = (__bf16)(o00[4 * rq + i] * inv0);
    *(uint2*)(yrow0 + 8 * rq + 4 * cH) = *(uint2*)ov;
#pragma unroll
    for (int i = 0; i < 4; ++i) ov[i] = (__bf16)(o10[4 * rq + i] * inv0);
    *(uint2*)(yrow0 + 32 + 8 * rq + 4 * cH) = *(uint2*)ov;
#pragma unroll
    for (int i = 0; i < 4; ++i) ov[i] = (__bf16)(o01[4 * rq + i] * inv1);
    *(uint2*)(yrow1 + 8 * rq + 4 * cH) = *(uint2*)ov;
#pragma unroll
    for (int i = 0; i < 4; ++i) ov[i] = (__bf16)(o11[4 * rq + i] * inv1);
    *(uint2*)(yrow1 + 32 + 8 * rq + 4 * cH) = *(uint2*)ov;
  }
#undef STAGE1
}

// ---------------- GEMM2: out = y @ W_proj + b_proj (fp32 out) ----------------
// 2-phase LDS double-buffer + conflict-free swizzled reads (T2) + XCD swizzle (T1).
__global__ __launch_bounds__(256) void k_gemm_proj(
    const __bf16* __restrict__ A, const __bf16* __restrict__ Bt,
    const float* __restrict__ bias, float* __restrict__ out) {
  __shared__ __align__(16) __bf16 As[2][128 * 32];
  __shared__ __align__(16) __bf16 Bs[2][128 * 32];
  const int tid = threadIdx.x;
  const int w = tid >> 6, l = tid & 63;
  const int l15 = l & 15, quad = l >> 4;
  const int wr = w >> 1, wc = w & 1;

  const int Lid = blockIdx.x + 8 * blockIdx.y;    // 512 blocks, 512 % 8 == 0
  const int xcd = Lid & 7;
  const int i64 = Lid >> 3;                       // [0,64)
  const int bx = i64 >> 3;                        // [0,8)
  const int by = (xcd << 3) + (i64 & 7);          // [0,64)
  const int bm0 = by * 128, bn0 = bx * 128;

  const int rs = w * 32 + (l >> 2);
  const int kc = ((l & 3) ^ ((l >> 3) & 3)) * 8;
  const __bf16* gA = A + (size_t)(bm0 + rs) * 1024 + kc;
  const __bf16* gB = Bt + (size_t)(bn0 + rs) * 1024 + kc;
  const int sq = (quad ^ ((l15 >> 1) & 3)) * 8;

  f32x4 acc[4][4] = {};

  gload_lds16(gA,             As[0] + w * 1024);
  gload_lds16(gA + 16 * 1024, As[0] + w * 1024 + 512);
  gload_lds16(gB,             Bs[0] + w * 1024);
  gload_lds16(gB + 16 * 1024, Bs[0] + w * 1024 + 512);
  __syncthreads();

  int buf = 0;
  for (int k0 = 0; k0 < 1024; k0 += 32) {
    if (k0 < 992) {
      const int nb = buf ^ 1;
      gload_lds16(gA + k0 + 32,             As[nb] + w * 1024);
      gload_lds16(gA + k0 + 32 + 16 * 1024, As[nb] + w * 1024 + 512);
      gload_lds16(gB + k0 + 32,             Bs[nb] + w * 1024);
      gload_lds16(gB + k0 + 32 + 16 * 1024, Bs[nb] + w * 1024 + 512);
    }
    bf16x8 af[4], bv[4];
#pragma unroll
    for (int mt = 0; mt < 4; ++mt)
      af[mt] = *(const bf16x8*)(As[buf] + (wr * 64 + mt * 16 + l15) * 32 + sq);
#pragma unroll
    for (int nt = 0; nt < 4; ++nt)
      bv[nt] = *(const bf16x8*)(Bs[buf] + (wc * 64 + nt * 16 + l15) * 32 + sq);
#pragma unroll
    for (int mt = 0; mt < 4; ++mt)
#pragma unroll
      for (int nt = 0; nt < 4; ++nt)
        acc[mt][nt] = MFMA16(af[mt], bv[nt], acc[mt][nt]);
    __syncthreads();
    buf ^= 1;
  }

#pragma unroll
  for (int nt = 0; nt < 4; ++nt) {
    const int n = bn0 + wc * 64 + nt * 16 + l15;
    const float bvv = bias[n];
#pragma unroll
    for (int mt = 0; mt < 4; ++mt) {
#pragma unroll
      for (int r = 0; r < 4; ++r) {
        const int m = bm0 + wr * 64 + mt * 16 + quad * 4 + r;
        out[(size_t)m * 1024 + n] = acc[mt][nt][r] + bvv;
      }
    }
  }
}

extern "C" void kernel_launch(void* const* d_in, const int* in_sizes, int n_in,
                              void* d_out, int out_size, void* d_ws, size_t ws_size,
                              hipStream_t stream) {
  const float* x      = (const float*)d_in[0];
  const float* W_attn = (const float*)d_in[1];
  const float* b_attn = (const float*)d_in[2];
  const float* W_proj = (const float*)d_in[3];
  const float* b_proj = (const float*)d_in[4];
  float* out = (float*)d_out;
  char* ws = (char*)d_ws;

  __bf16* xb  = (__bf16*)(ws);                     // 16 MiB  x bf16; later reused as y
  __bf16* WaT = (__bf16*)(ws + (16ull << 20));     //  6 MiB  W_attn^T bf16
  __bf16* WpT = (__bf16*)(ws + (22ull << 20));     //  2 MiB  W_proj^T bf16
  __bf16* Qg  = (__bf16*)(ws + (24ull << 20));     // 16 MiB  Q*SC [bh][T][64]
  __bf16* Kg  = (__bf16*)(ws + (40ull << 20));     // 16 MiB  K [bh][T][64]
  __bf16* VTg = (__bf16*)(ws + (56ull << 20));     // 16 MiB  V^T [bh][64][T]

  k_cvt<<<8192, 256, 0, stream>>>(x, xb, 2097152);
  k_transpose<<<dim3(96, 32), 256, 0, stream>>>(W_attn, WaT, 1024, 3072);
  k_transpose<<<dim3(32, 32), 256, 0, stream>>>(W_proj, WpT, 1024, 1024);
  k_gemm_qkv<<<dim3(12, 32), 512, 0, stream>>>(xb, WaT, b_attn, Qg, Kg, VTg);
  k_attn<<<dim3(64, 32), 64, 0, stream>>>(Qg, Kg, VTg, xb /* y reuses xb */);
  k_gemm_proj<<<dim3(8, 64), 256, 0, stream>>>(xb, WpT, b_proj, out);
}

// Round 6
// 238.567 us; speedup vs baseline: 1.0625x; 1.0625x over previous
//
#include <hip/hip_runtime.h>
#include <cstdint>

// Problem constants: B=4, T=2048, D=1024, H=16, hd=64
#define MFMA16(a, b, c) __builtin_amdgcn_mfma_f32_16x16x32_bf16(a, b, c, 0, 0, 0)
#define MFMA32(a, b, c) __builtin_amdgcn_mfma_f32_32x32x16_bf16(a, b, c, 0, 0, 0)

typedef float  f32x4   __attribute__((ext_vector_type(4)));
typedef float  f32x16  __attribute__((ext_vector_type(16)));
typedef __bf16 bf16x8  __attribute__((ext_vector_type(8)));
typedef short  s16x4   __attribute__((ext_vector_type(4)));
typedef __bf16 bf16x4  __attribute__((ext_vector_type(4)));

// ---- K=8 MFMA for the PV stage: B-fragment (k = 4*cH + j) matches the S-tile
// C-layout rows per lane exactly -> no cross-lane P transform needed at all.
#if __has_builtin(__builtin_amdgcn_mfma_f32_32x32x8bf16_1k)
#define HAVE_MFMA8 1
__device__ __forceinline__ f32x16 MFMA8(uint32_t a0, uint32_t a1,
                                        uint32_t b0, uint32_t b1, f32x16 c) {
  union { uint32_t u[2]; s16x4 v; } ua, ub;
  ua.u[0] = a0; ua.u[1] = a1; ub.u[0] = b0; ub.u[1] = b1;
  return __builtin_amdgcn_mfma_f32_32x32x8bf16_1k(ua.v, ub.v, c, 0, 0, 0);
}
#elif __has_builtin(__builtin_amdgcn_mfma_f32_32x32x8_bf16)
#define HAVE_MFMA8 1
__device__ __forceinline__ f32x16 MFMA8(uint32_t a0, uint32_t a1,
                                        uint32_t b0, uint32_t b1, f32x16 c) {
  union { uint32_t u[2]; bf16x4 v; } ua, ub;
  ua.u[0] = a0; ua.u[1] = a1; ub.u[0] = b0; ub.u[1] = b1;
  return __builtin_amdgcn_mfma_f32_32x32x8_bf16(ua.v, ub.v, c, 0, 0, 0);
}
#else
#define HAVE_MFMA8 0
#endif

__device__ __forceinline__ void gload_lds16(const void* g, const void* l) {
  __builtin_amdgcn_global_load_lds(
      (const __attribute__((address_space(1))) unsigned int*)(uintptr_t)g,
      (__attribute__((address_space(3))) unsigned int*)(unsigned int)(uintptr_t)l,
      16, 0, 0);
}

__device__ __forceinline__ uint32_t pack_bf16(float a, float b) {
  union { __bf16 h[2]; uint32_t u; } u;
  u.h[0] = (__bf16)a; u.h[1] = (__bf16)b;
  return u.u;
}

__device__ __forceinline__ float fexp2(float x) { return __builtin_amdgcn_exp2f(x); }

// ---------------- fp32 -> bf16 convert (vectorized) ----------------
__global__ void k_cvt(const float* __restrict__ in, __bf16* __restrict__ out, int n4) {
  int i = blockIdx.x * 256 + threadIdx.x;
  if (i >= n4) return;
  float4 v = reinterpret_cast<const float4*>(in)[i];
  __bf16 o[4] = {(__bf16)v.x, (__bf16)v.y, (__bf16)v.z, (__bf16)v.w};
  *reinterpret_cast<uint2*>(out + (size_t)i * 4) = *reinterpret_cast<const uint2*>(o);
}

// ---------------- fp32 [R][C] -> bf16 [C][R] tiled transpose ----------------
__global__ void k_transpose(const float* __restrict__ in, __bf16* __restrict__ out,
                            int R, int C) {
  __shared__ float tile[32][33];
  const int c0 = blockIdx.x * 32, r0 = blockIdx.y * 32;
  const int x = threadIdx.x & 31, y = threadIdx.x >> 5;
#pragma unroll
  for (int i = 0; i < 4; ++i)
    tile[y + i * 8][x] = in[(size_t)(r0 + y + i * 8) * C + c0 + x];
  __syncthreads();
#pragma unroll
  for (int i = 0; i < 4; ++i)
    out[(size_t)(c0 + y + i * 8) * R + r0 + x] = (__bf16)tile[x][y + i * 8];
}

// ---------------- GEMM1: qkv = x @ W_attn + b_attn, scattered to Q/K/VT ----
// 256x256 tile, BK=64, 8 waves (2M x 4N), 128 KiB LDS, 8-phase schedule with
// counted vmcnt (T3+T4), XOR LDS swizzle both-sides (T2, rule 21), setprio (T5),
// bijective XCD swizzle (T1).
#define STG_A(kt, h, b)                                                        \
  do {                                                                         \
    gload_lds16(gA0 + (h) * 131072 + (kt) * 64,                                \
                GS + (b) * 32768 + (h) * 16384 + tid * 16);                    \
    gload_lds16(gA0 + (h) * 131072 + 65536 + (kt) * 64,                        \
                GS + (b) * 32768 + (h) * 16384 + 8192 + tid * 16);             \
  } while (0)
#define STG_B(kt, h, b)                                                        \
  do {                                                                         \
    gload_lds16(gB0 + (h) * 131072 + (kt) * 64,                                \
                GS + 65536 + (b) * 32768 + (h) * 16384 + tid * 16);            \
    gload_lds16(gB0 + (h) * 131072 + 65536 + (kt) * 64,                        \
                GS + 65536 + (b) * 32768 + (h) * 16384 + 8192 + tid * 16);     \
  } while (0)

#define WAITV4 __asm__ volatile("s_waitcnt vmcnt(4)" ::: "memory")
#define NOWAIT (void)0

#define PH(mhv, ksv, bufv, READB, STAGE_STMT, TAILWAIT)                        \
  do {                                                                         \
    bf16x8 aF_[4];                                                             \
    const char* Ap_ = GS + (bufv) * 32768 + Abase + (mhv) * 8192;              \
    _Pragma("unroll") for (int i_ = 0; i_ < 4; ++i_)                           \
        aF_[i_] = *(const bf16x8*)(Ap_ + i_ * 2048 + swz[ksv]);                \
    if (READB) {                                                               \
      const char* Bp_ = GS + (bufv) * 32768 + Bbase;                           \
      _Pragma("unroll") for (int n_ = 0; n_ < 4; ++n_)                         \
          bK[ksv][n_] = *(const bf16x8*)(Bp_ + n_ * 2048 + swz[ksv]);          \
    }                                                                          \
    STAGE_STMT;                                                                \
    __builtin_amdgcn_s_barrier();                                              \
    __asm__ volatile("s_waitcnt lgkmcnt(0)" ::: "memory");                     \
    __builtin_amdgcn_s_setprio(1);                                             \
    _Pragma("unroll") for (int i_ = 0; i_ < 4; ++i_)                           \
        _Pragma("unroll") for (int n_ = 0; n_ < 4; ++n_)                       \
            acc[(mhv) * 4 + i_][n_] =                                          \
                MFMA16(aF_[i_], bK[ksv][n_], acc[(mhv) * 4 + i_][n_]);         \
    __builtin_amdgcn_s_setprio(0);                                             \
    TAILWAIT;                                                                  \
    __builtin_amdgcn_s_barrier();                                              \
  } while (0)

__global__ __launch_bounds__(512, 2) void k_gemm_qkv(
    const __bf16* __restrict__ A, const __bf16* __restrict__ Bt,
    const float* __restrict__ bias,
    __bf16* __restrict__ Qg, __bf16* __restrict__ Kg, __bf16* __restrict__ VTg) {
  __shared__ __align__(16) char GS[131072];
  const int tid = threadIdx.x;
  const int w = tid >> 6, l = tid & 63;
  const int l15 = l & 15, quad = l >> 4;
  const int wr = w >> 2, wc = w & 3;           // 2M x 4N wave grid

  // T1 bijective XCD swizzle: HW linear id L (x-fastest) -> XCD = L % 8.
  // XCD c gets rows by in [4c,4c+4), visited y-fastest within the chunk.
  const int Lid = blockIdx.x + 12 * blockIdx.y;   // 384 blocks, 384 % 8 == 0
  const int xcd = Lid & 7;
  const int i48 = Lid >> 3;                       // [0,48)
  const int bx = i48 >> 2;                        // [0,12)
  const int by = (xcd << 2) + (i48 & 3);          // [0,32)
  const int bm0 = by * 256, bn0 = bx * 256;
  const int which = bx >> 2;                      // 0 Q, 1 K, 2 V (block-uniform)
  const float SC = 0.18033688011112042f;

  const int srow = tid >> 3;
  const int scol = ((tid & 7) ^ (srow & 7)) * 8;
  const __bf16* gA0 = A + (size_t)(bm0 + srow) * 1024 + scol;
  const __bf16* gB0 = Bt + (size_t)(bn0 + srow) * 1024 + scol;

  const int Abase = wr * 16384 + l15 * 128;
  const int Bbase = 65536 + (wc >> 1) * 16384 + (wc & 1) * 8192 + l15 * 128;
  int swz[2];
  swz[0] = ((0 + quad) ^ (l15 & 7)) * 16;
  swz[1] = ((4 + quad) ^ (l15 & 7)) * 16;

  f32x4 acc[8][4] = {};
  bf16x8 bK[2][4];

  STG_B(0, 0, 0); STG_B(0, 1, 0);
  STG_A(0, 0, 0); STG_A(0, 1, 0);
  STG_B(1, 0, 1); STG_B(1, 1, 1);
  __asm__ volatile("s_waitcnt vmcnt(4)" ::: "memory");
  __builtin_amdgcn_s_barrier();

#pragma unroll 1
  for (int u = 0; u < 8; ++u) {
    const int kA1 = 2 * u + 1;
    const int kN0 = 2 * u + 2;
    const int kN1 = 2 * u + 3;
    PH(0, 0, 0, true,  STG_A(kA1, 0, 1), NOWAIT);
    PH(0, 1, 0, true,  STG_A(kA1, 1, 1), NOWAIT);
    PH(1, 0, 0, false, STG_B(kN0, 0, 0), NOWAIT);
    PH(1, 1, 0, false, STG_B(kN0, 1, 0), WAITV4);
    PH(0, 0, 1, true,  STG_A(kN0, 0, 0), NOWAIT);
    PH(0, 1, 1, true,  STG_A(kN0, 1, 0), NOWAIT);
    PH(1, 0, 1, false, STG_B(kN1, 0, 1), NOWAIT);
    PH(1, 1, 1, false, STG_B(kN1, 1, 1), WAITV4);
  }

  __asm__ volatile("s_waitcnt vmcnt(0) lgkmcnt(0)" ::: "memory");
  __syncthreads();

  if (which < 2) {
    __bf16* dst = which == 0 ? Qg : Kg;
    const float mul = which == 0 ? SC : 1.0f;
    const int hh = ((bn0 & 1023) >> 6) + wc;
    const int bb = bm0 >> 11;
    const int tt0 = (bm0 & 2047) + wr * 128;
    float bv4[4];
#pragma unroll
    for (int nf = 0; nf < 4; ++nf) bv4[nf] = bias[bn0 + wc * 64 + nf * 16 + l15];
    __bf16* TR = (__bf16*)(GS + w * 2304);
    const int rrow = l >> 2, cc = l & 3;
    __bf16* gbase = dst + ((size_t)(bb * 16 + hh) * 2048 + tt0) * 64;
#pragma unroll
    for (int f = 0; f < 8; ++f) {
#pragma unroll
      for (int nf = 0; nf < 4; ++nf)
#pragma unroll
        for (int r = 0; r < 4; ++r)
          TR[(quad * 4 + r) * 72 + nf * 16 + l15] =
              (__bf16)((acc[f][nf][r] + bv4[nf]) * mul);
      __asm__ volatile("s_waitcnt lgkmcnt(0)" ::: "memory");
      uint4 v0 = *(const uint4*)(TR + rrow * 72 + cc * 8);
      uint4 v1 = *(const uint4*)(TR + rrow * 72 + cc * 8 + 32);
      __bf16* gp = gbase + (size_t)(f * 16 + rrow) * 64 + cc * 8;
      *(uint4*)gp = v0;
      *(uint4*)(gp + 32) = v1;
      __asm__ volatile("" ::: "memory");
    }
  } else {
    const int hv = (bn0 + wc * 64 - 2048) >> 6;
    const int bb = bm0 >> 11;
    float bv4[4];
#pragma unroll
    for (int nf = 0; nf < 4; ++nf) bv4[nf] = bias[bn0 + wc * 64 + nf * 16 + l15];
    __bf16* VL = (__bf16*)(GS + w * 9216);
    const int t0base = (bm0 & 2047) + wr * 128;
    __bf16* vrowb = VTg + (size_t)(bb * 16 + hv) * 64 * 2048;
#pragma unroll
    for (int pg = 0; pg < 2; ++pg) {
#pragma unroll
      for (int fi = 0; fi < 4; ++fi) {
#pragma unroll
        for (int nf = 0; nf < 4; ++nf)
#pragma unroll
          for (int r = 0; r < 4; ++r)
            VL[(nf * 16 + l15) * 72 + fi * 16 + quad * 4 + r] =
                (__bf16)(acc[pg * 4 + fi][nf][r] + bv4[nf]);
      }
      __asm__ volatile("s_waitcnt lgkmcnt(0)" ::: "memory");
      const int c = l & 7;
#pragma unroll
      for (int it = 0; it < 8; ++it) {
        const int dr = (l >> 3) + 8 * it;
        uint4 vv = *(const uint4*)(VL + dr * 72 + c * 8);
        *(uint4*)(vrowb + (size_t)dr * 2048 + t0base + pg * 64 + c * 8) = vv;
      }
      __asm__ volatile("" ::: "memory");
    }
  }
}

// ---------------- Flash attention: 8 waves, split-kv, 32x32 MFMA ----------------
// R0-exact structure (best measured: 64.4 us) + T5 setprio around MFMA clusters.
// Grid (64, 8), 512 threads. Block handles q-tiles {p, 15-p} for bh=blockIdx.x
// -> every block has EQUAL total work (17 j-iters); 2 blocks/CU (66.5 KiB LDS).
// Waves: wq = w&3 (q sub-tile of 32 rows), hf = w>>2 (kv half). Each barrier
// interval stages 128 kv rows; half hf computes tile 2j+hf.
// Fixed-max softmax (exact by shift-invariance); PV via K=8 MFMA: the packed
// P dwords ARE the B-fragment (k = 4cH+j) -> zero cross-lane transform.
__global__ __launch_bounds__(512) void k_attn(
    const __bf16* __restrict__ Qg, const __bf16* __restrict__ Kg,
    const __bf16* __restrict__ VTg, __bf16* __restrict__ yb) {
  __shared__ __align__(16) char smem[66560];
  const int tid = threadIdx.x;
  const int w = tid >> 6, l = tid & 63;
  const int wq = w & 3, hf = w >> 2, wqh = wq >> 1;
  const int l31 = l & 31, cH = l >> 5;
  const int bh = blockIdx.x;
  const int bb = bh >> 4, h = bh & 15;
  const __bf16* Qb = Qg + (size_t)bh * 2048 * 64;

  // staging addresses
  const int rk = w * 8 + (l >> 3);
  const __bf16* gK = Kg + ((size_t)bh * 2048 + rk) * 64 + (((l & 7) ^ (rk & 7)) * 8);
  const int rv = w * 4 + (l >> 4);
  const int rvB = rv + 32;
  const __bf16* gVA = VTg + ((size_t)bh * 64 + rv) * 2048 +
                      (((l & 8) | ((l & 7) ^ (rv & 7))) * 8);
  const __bf16* gVB = VTg + ((size_t)bh * 64 + rvB) * 2048 +
                      (((l & 8) | ((l & 7) ^ (rvB & 7))) * 8);

  // lane-constant LDS read offsets (bytes), hoisted out of the k-loop
  const int R0 = 64 * hf + l31;
  int koff[4], koff1[4];
#pragma unroll
  for (int s = 0; s < 4; ++s) {
    koff[s]  = R0 * 64 * 2 + (((2 * s + cH) ^ (R0 & 7)) * 16);
    koff1[s] = (R0 + 32) * 64 * 2 + (((2 * s + cH) ^ (R0 & 7)) * 16);
  }
#if HAVE_MFMA8
  int voff[2][4], voff1[2][4];
#pragma unroll
  for (int kvt = 0; kvt < 2; ++kvt)
#pragma unroll
    for (int g = 0; g < 4; ++g) {
      const int slot = (8 * hf) | ((4 * kvt + g) ^ (l31 & 7));
      voff[kvt][g]  = l31 * 256 + slot * 16 + 8 * cH;
      voff1[kvt][g] = (32 + l31) * 256 + slot * 16 + 8 * cH;
    }
#else
  int voffL[4], voffL1[4];
#pragma unroll
  for (int s = 0; s < 4; ++s) {
    const int sl0 = (8 * hf) | ((2 * s + cH) ^ (l31 & 7));
    voffL[s]  = l31 * 256 + sl0 * 16;
    voffL1[s] = (32 + l31) * 256 + sl0 * 16;
  }
#endif

  for (int seg = 0; seg < 2; ++seg) {
    const int p = seg ? 15 - blockIdx.y : blockIdx.y;
    const int qt0 = p * 128 + wq * 32;
    const int q = qt0 + l31;

    __syncthreads();

    bf16x8 qf[4];
#pragma unroll
    for (int s = 0; s < 4; ++s)
      qf[s] = *(const bf16x8*)(Qb + (size_t)q * 64 + s * 16 + cH * 8);

    f32x16 o0 = {}, o1 = {};
    float lsum = 0.f;

    {
      char* KSb = smem;
      char* VSb = smem + 32768;
      gload_lds16(gK,           KSb + w * 1024);
      gload_lds16(gK + 64 * 64, KSb + 8192 + w * 1024);
      gload_lds16(gVA,          VSb + w * 1024);
      gload_lds16(gVB,          VSb + 8192 + w * 1024);
    }

    for (int j = 0; j <= p; ++j) {
      __syncthreads();
      if (j < p) {
        const int b2 = (j + 1) & 1;
        char* KSb = smem + b2 * 16384;
        char* VSb = smem + 32768 + b2 * 16384;
        const size_t ko = (size_t)(128 * (j + 1)) * 64;
        gload_lds16(gK + ko,             KSb + w * 1024);
        gload_lds16(gK + ko + 64 * 64,   KSb + 8192 + w * 1024);
        gload_lds16(gVA + 128 * (j + 1), VSb + w * 1024);
        gload_lds16(gVB + 128 * (j + 1), VSb + 8192 + w * 1024);
      }
      const bool act = (j < p) || (hf <= wqh);
      if (act) {
        const bool diag = (j == p) && (hf == wqh);
        const char* KSb = smem + (j & 1) * 16384;
        const char* VSb = smem + 32768 + (j & 1) * 16384;
        const int kv0 = (2 * j + hf) * 64;

        bf16x8 kf0[4], kf1[4];
#pragma unroll
        for (int s = 0; s < 4; ++s) {
          kf0[s] = *(const bf16x8*)(KSb + koff[s]);
          kf1[s] = *(const bf16x8*)(KSb + koff1[s]);
        }
        f32x16 st0 = {}, st1 = {};
        __builtin_amdgcn_s_setprio(1);
#pragma unroll
        for (int s = 0; s < 4; ++s) st0 = MFMA32(kf0[s], qf[s], st0);
#pragma unroll
        for (int s = 0; s < 4; ++s) st1 = MFMA32(kf1[s], qf[s], st1);
        __builtin_amdgcn_s_setprio(0);

        if (diag) {
          const int base0 = kv0 + 4 * cH;
          const int base1 = kv0 + 32 + 4 * cH;
#pragma unroll
          for (int r = 0; r < 16; ++r) {
            const int off = (r & 3) + 8 * (r >> 2);
            if (base0 + off > q) st0[r] = -1e30f;
            if (base1 + off > q) st1[r] = -1e30f;
          }
        }

        // exp2 (fixed max 0), pairwise-tree sum, pack to bf16 dwords
        uint32_t pk[2][4][2];
        float sacc[2];
#pragma unroll
        for (int kvt = 0; kvt < 2; ++kvt) {
          float pp[16];
#pragma unroll
          for (int r = 0; r < 16; ++r) pp[r] = fexp2(kvt ? st1[r] : st0[r]);
          float s01 = (pp[0] + pp[1]) + (pp[2] + pp[3]);
          float s23 = (pp[4] + pp[5]) + (pp[6] + pp[7]);
          float s45 = (pp[8] + pp[9]) + (pp[10] + pp[11]);
          float s67 = (pp[12] + pp[13]) + (pp[14] + pp[15]);
          sacc[kvt] = (s01 + s23) + (s45 + s67);
#pragma unroll
          for (int rq = 0; rq < 4; ++rq) {
            pk[kvt][rq][0] = pack_bf16(pp[4 * rq], pp[4 * rq + 1]);
            pk[kvt][rq][1] = pack_bf16(pp[4 * rq + 2], pp[4 * rq + 3]);
          }
        }
        lsum += sacc[0] + sacc[1];

#if HAVE_MFMA8
        // PV: K=8 MFMA, pk dwords are the B-fragment directly (no shuffles)
        __builtin_amdgcn_s_setprio(1);
#pragma unroll
        for (int kvt = 0; kvt < 2; ++kvt)
#pragma unroll
          for (int g = 0; g < 4; ++g) {
            const uint2 va = *(const uint2*)(VSb + voff[kvt][g]);
            const uint2 vb = *(const uint2*)(VSb + voff1[kvt][g]);
            o0 = MFMA8(va.x, va.y, pk[kvt][g][0], pk[kvt][g][1], o0);
            o1 = MFMA8(vb.x, vb.y, pk[kvt][g][0], pk[kvt][g][1], o1);
          }
        __builtin_amdgcn_s_setprio(0);
#else
        // fallback: K=16 MFMA with bpermute-based B-fragment assembly
        bf16x8 vf0[4], vf1[4];
#pragma unroll
        for (int s = 0; s < 4; ++s) {
          vf0[s] = *(const bf16x8*)(VSb + voffL[s]);
          vf1[s] = *(const bf16x8*)(VSb + voffL1[s]);
        }
#pragma unroll
        for (int s = 0; s < 4; ++s) {
          const int kvt = s >> 1;
          const int rq_own = 2 * (s & 1) + cH;
          const int rq_snd = 2 * (s & 1) + 1 - cH;
          const uint32_t own0 = pk[kvt][rq_own][0], own1 = pk[kvt][rq_own][1];
          const uint32_t rcv0 = (uint32_t)__shfl_xor((int)pk[kvt][rq_snd][0], 32, 64);
          const uint32_t rcv1 = (uint32_t)__shfl_xor((int)pk[kvt][rq_snd][1], 32, 64);
          union { uint32_t u[4]; bf16x8 v; } pf;
          pf.u[0] = cH ? rcv0 : own0;
          pf.u[1] = cH ? rcv1 : own1;
          pf.u[2] = cH ? own0 : rcv0;
          pf.u[3] = cH ? own1 : rcv1;
          o0 = MFMA32(vf0[s], pf.v, o0);
          o1 = MFMA32(vf1[s], pf.v, o1);
        }
#endif
      }
    }

    // split-kv merge: half1 writes (o, sum) to LDS; half0 combines and stores y
    __syncthreads();
    float4* Msh = (float4*)smem;
    float* Ls2 = (float*)(smem + 65536);
    const float stot = lsum + __shfl_xor(lsum, 32, 64);
    union { f32x16 v; float4 q4[4]; } u0, u1;
    u0.v = o0; u1.v = o1;
    if (hf == 1) {
#pragma unroll
      for (int i = 0; i < 4; ++i) {
        Msh[(i * 4 + wq) * 64 + l] = u0.q4[i];
        Msh[((i + 4) * 4 + wq) * 64 + l] = u1.q4[i];
      }
      Ls2[wq * 64 + l] = stot;
    }
    __syncthreads();
    if (hf == 0) {
#pragma unroll
      for (int i = 0; i < 4; ++i) {
        float4 a = Msh[(i * 4 + wq) * 64 + l];
        float4 b2 = Msh[((i + 4) * 4 + wq) * 64 + l];
        u0.q4[i].x += a.x; u0.q4[i].y += a.y; u0.q4[i].z += a.z; u0.q4[i].w += a.w;
        u1.q4[i].x += b2.x; u1.q4[i].y += b2.y; u1.q4[i].z += b2.z; u1.q4[i].w += b2.w;
      }
      const float inv = 1.0f / (stot + Ls2[wq * 64 + l]);
      __bf16* yrow = yb + ((size_t)(bb * 2048 + q)) * 1024 + h * 64;
#pragma unroll
      for (int dt = 0; dt < 2; ++dt) {
        const f32x16& o = dt ? u1.v : u0.v;
#pragma unroll
        for (int rq = 0; rq < 4; ++rq) {
          __bf16 ov[4];
#pragma unroll
          for (int i = 0; i < 4; ++i) ov[i] = (__bf16)(o[4 * rq + i] * inv);
          *(uint2*)(yrow + dt * 32 + 8 * rq + 4 * cH) = *(uint2*)ov;
        }
      }
    }
  }
}

// ---------------- GEMM2: out = y @ W_proj + b_proj (fp32 out) ----------------
// 2-phase LDS double-buffer + conflict-free swizzled reads (T2) + XCD swizzle (T1).
__global__ __launch_bounds__(256) void k_gemm_proj(
    const __bf16* __restrict__ A, const __bf16* __restrict__ Bt,
    const float* __restrict__ bias, float* __restrict__ out) {
  __shared__ __align__(16) __bf16 As[2][128 * 32];
  __shared__ __align__(16) __bf16 Bs[2][128 * 32];
  const int tid = threadIdx.x;
  const int w = tid >> 6, l = tid & 63;
  const int l15 = l & 15, quad = l >> 4;
  const int wr = w >> 1, wc = w & 1;

  const int Lid = blockIdx.x + 8 * blockIdx.y;    // 512 blocks, 512 % 8 == 0
  const int xcd = Lid & 7;
  const int i64 = Lid >> 3;                       // [0,64)
  const int bx = i64 >> 3;                        // [0,8)
  const int by = (xcd << 3) + (i64 & 7);          // [0,64)
  const int bm0 = by * 128, bn0 = bx * 128;

  const int rs = w * 32 + (l >> 2);
  const int kc = ((l & 3) ^ ((l >> 3) & 3)) * 8;
  const __bf16* gA = A + (size_t)(bm0 + rs) * 1024 + kc;
  const __bf16* gB = Bt + (size_t)(bn0 + rs) * 1024 + kc;
  const int sq = (quad ^ ((l15 >> 1) & 3)) * 8;

  f32x4 acc[4][4] = {};

  gload_lds16(gA,             As[0] + w * 1024);
  gload_lds16(gA + 16 * 1024, As[0] + w * 1024 + 512);
  gload_lds16(gB,             Bs[0] + w * 1024);
  gload_lds16(gB + 16 * 1024, Bs[0] + w * 1024 + 512);
  __syncthreads();

  int buf = 0;
  for (int k0 = 0; k0 < 1024; k0 += 32) {
    if (k0 < 992) {
      const int nb = buf ^ 1;
      gload_lds16(gA + k0 + 32,             As[nb] + w * 1024);
      gload_lds16(gA + k0 + 32 + 16 * 1024, As[nb] + w * 1024 + 512);
      gload_lds16(gB + k0 + 32,             Bs[nb] + w * 1024);
      gload_lds16(gB + k0 + 32 + 16 * 1024, Bs[nb] + w * 1024 + 512);
    }
    bf16x8 af[4], bv[4];
#pragma unroll
    for (int mt = 0; mt < 4; ++mt)
      af[mt] = *(const bf16x8*)(As[buf] + (wr * 64 + mt * 16 + l15) * 32 + sq);
#pragma unroll
    for (int nt = 0; nt < 4; ++nt)
      bv[nt] = *(const bf16x8*)(Bs[buf] + (wc * 64 + nt * 16 + l15) * 32 + sq);
#pragma unroll
    for (int mt = 0; mt < 4; ++mt)
#pragma unroll
      for (int nt = 0; nt < 4; ++nt)
        acc[mt][nt] = MFMA16(af[mt], bv[nt], acc[mt][nt]);
    __syncthreads();
    buf ^= 1;
  }

#pragma unroll
  for (int nt = 0; nt < 4; ++nt) {
    const int n = bn0 + wc * 64 + nt * 16 + l15;
    const float bvv = bias[n];
#pragma unroll
    for (int mt = 0; mt < 4; ++mt) {
#pragma unroll
      for (int r = 0; r < 4; ++r) {
        const int m = bm0 + wr * 64 + mt * 16 + quad * 4 + r;
        out[(size_t)m * 1024 + n] = acc[mt][nt][r] + bvv;
      }
    }
  }
}

extern "C" void kernel_launch(void* const* d_in, const int* in_sizes, int n_in,
                              void* d_out, int out_size, void* d_ws, size_t ws_size,
                              hipStream_t stream) {
  const float* x      = (const float*)d_in[0];
  const float* W_attn = (const float*)d_in[1];
  const float* b_attn = (const float*)d_in[2];
  const float* W_proj = (const float*)d_in[3];
  const float* b_proj = (const float*)d_in[4];
  float* out = (float*)d_out;
  char* ws = (char*)d_ws;

  __bf16* xb  = (__bf16*)(ws);                     // 16 MiB  x bf16; later reused as y
  __bf16* WaT = (__bf16*)(ws + (16ull << 20));     //  6 MiB  W_attn^T bf16
  __bf16* WpT = (__bf16*)(ws + (22ull << 20));     //  2 MiB  W_proj^T bf16
  __bf16* Qg  = (__bf16*)(ws + (24ull << 20));     // 16 MiB  Q*SC [bh][T][64]
  __bf16* Kg  = (__bf16*)(ws + (40ull << 20));     // 16 MiB  K [bh][T][64]
  __bf16* VTg = (__bf16*)(ws + (56ull << 20));     // 16 MiB  V^T [bh][64][T]

  k_cvt<<<8192, 256, 0, stream>>>(x, xb, 2097152);
  k_transpose<<<dim3(96, 32), 256, 0, stream>>>(W_attn, WaT, 1024, 3072);
  k_transpose<<<dim3(32, 32), 256, 0, stream>>>(W_proj, WpT, 1024, 1024);
  k_gemm_qkv<<<dim3(12, 32), 512, 0, stream>>>(xb, WaT, b_attn, Qg, Kg, VTg);
  k_attn<<<dim3(64, 8), 512, 0, stream>>>(Qg, Kg, VTg, xb /* y reuses xb */);
  k_gemm_proj<<<dim3(8, 64), 256, 0, stream>>>(xb, WpT, b_proj, out);
}

// Round 7
// 231.669 us; speedup vs baseline: 1.0941x; 1.0298x over previous
//
#include <hip/hip_runtime.h>
#include <cstdint>

// Problem constants: B=4, T=2048, D=1024, H=16, hd=64
#define MFMA16(a, b, c) __builtin_amdgcn_mfma_f32_16x16x32_bf16(a, b, c, 0, 0, 0)
#define MFMA32(a, b, c) __builtin_amdgcn_mfma_f32_32x32x16_bf16(a, b, c, 0, 0, 0)

typedef float  f32x4   __attribute__((ext_vector_type(4)));
typedef float  f32x16  __attribute__((ext_vector_type(16)));
typedef __bf16 bf16x8  __attribute__((ext_vector_type(8)));
typedef short  s16x4   __attribute__((ext_vector_type(4)));
typedef __bf16 bf16x4  __attribute__((ext_vector_type(4)));

// ---- K=8 MFMA for the PV stage: B-fragment (k = 4*cH + j) matches the S-tile
// C-layout rows per lane exactly -> no cross-lane P transform needed at all.
#if __has_builtin(__builtin_amdgcn_mfma_f32_32x32x8bf16_1k)
#define HAVE_MFMA8 1
__device__ __forceinline__ f32x16 MFMA8(uint32_t a0, uint32_t a1,
                                        uint32_t b0, uint32_t b1, f32x16 c) {
  union { uint32_t u[2]; s16x4 v; } ua, ub;
  ua.u[0] = a0; ua.u[1] = a1; ub.u[0] = b0; ub.u[1] = b1;
  return __builtin_amdgcn_mfma_f32_32x32x8bf16_1k(ua.v, ub.v, c, 0, 0, 0);
}
#elif __has_builtin(__builtin_amdgcn_mfma_f32_32x32x8_bf16)
#define HAVE_MFMA8 1
__device__ __forceinline__ f32x16 MFMA8(uint32_t a0, uint32_t a1,
                                        uint32_t b0, uint32_t b1, f32x16 c) {
  union { uint32_t u[2]; bf16x4 v; } ua, ub;
  ua.u[0] = a0; ua.u[1] = a1; ub.u[0] = b0; ub.u[1] = b1;
  return __builtin_amdgcn_mfma_f32_32x32x8_bf16(ua.v, ub.v, c, 0, 0, 0);
}
#else
#define HAVE_MFMA8 0
#endif

__device__ __forceinline__ void gload_lds16(const void* g, const void* l) {
  __builtin_amdgcn_global_load_lds(
      (const __attribute__((address_space(1))) unsigned int*)(uintptr_t)g,
      (__attribute__((address_space(3))) unsigned int*)(unsigned int)(uintptr_t)l,
      16, 0, 0);
}

__device__ __forceinline__ uint32_t pack_bf16(float a, float b) {
  union { __bf16 h[2]; uint32_t u; } u;
  u.h[0] = (__bf16)a; u.h[1] = (__bf16)b;
  return u.u;
}

__device__ __forceinline__ float fexp2(float x) { return __builtin_amdgcn_exp2f(x); }

// ---------------- fp32 -> bf16 convert (vectorized) ----------------
__global__ void k_cvt(const float* __restrict__ in, __bf16* __restrict__ out, int n4) {
  int i = blockIdx.x * 256 + threadIdx.x;
  if (i >= n4) return;
  float4 v = reinterpret_cast<const float4*>(in)[i];
  __bf16 o[4] = {(__bf16)v.x, (__bf16)v.y, (__bf16)v.z, (__bf16)v.w};
  *reinterpret_cast<uint2*>(out + (size_t)i * 4) = *reinterpret_cast<const uint2*>(o);
}

// ---------------- fp32 [R][C] -> bf16 [C][R] tiled transpose ----------------
__global__ void k_transpose(const float* __restrict__ in, __bf16* __restrict__ out,
                            int R, int C) {
  __shared__ float tile[32][33];
  const int c0 = blockIdx.x * 32, r0 = blockIdx.y * 32;
  const int x = threadIdx.x & 31, y = threadIdx.x >> 5;
#pragma unroll
  for (int i = 0; i < 4; ++i)
    tile[y + i * 8][x] = in[(size_t)(r0 + y + i * 8) * C + c0 + x];
  __syncthreads();
#pragma unroll
  for (int i = 0; i < 4; ++i)
    out[(size_t)(c0 + y + i * 8) * R + r0 + x] = (__bf16)tile[x][y + i * 8];
}

// ---------------- GEMM1: qkv = x @ W_attn + b_attn, scattered to Q/K/VT ----
// 256x128 tile, BK=64, 8 waves (2M x 4N, 32 cols/wave -> head-aligned), LDS
// triple-buffered 144 KiB (A 3x32K, B 3x16K): grid 24x32 = 768 blocks = EXACTLY
// 3 full rounds at 1 block/CU (the 384-block version wasted 25% on a half-idle
// second round). 2 phases/K-tile, 16 MFMA/phase; during tile u we stage tile
// u+2 (3 gloads per phase); s_waitcnt vmcnt(6) once per tile (never 0).
// T2 XOR swizzle both-sides; T1 bijective XCD swizzle.
#define STGA_CALL(kt, b, i)                                                    \
  gload_lds16(gA0 + (i) * 65536 + (kt) * 64,                                   \
              GS + (b) * 32768 + (i) * 8192 + tid * 16)
#define STGB_CALL(kt, b, i)                                                    \
  gload_lds16(gB0 + (i) * 65536 + (kt) * 64,                                   \
              GS + 98304 + (b) * 16384 + (i) * 8192 + tid * 16)

#define WAITV6 __asm__ volatile("s_waitcnt vmcnt(6)" ::: "memory")
#define NOWAIT (void)0

#define PH2(ksv, bufv, STAGE_STMT, TAILWAIT)                                   \
  do {                                                                         \
    bf16x8 aF_[8], bF_[2];                                                     \
    const char* Ap_ = GS + (bufv) * 32768 + Abase;                             \
    _Pragma("unroll") for (int f_ = 0; f_ < 8; ++f_)                           \
        aF_[f_] = *(const bf16x8*)(Ap_ + f_ * 2048 + swz[ksv]);                \
    const char* Bp_ = GS + 98304 + (bufv) * 16384 + Bbase;                     \
    _Pragma("unroll") for (int n_ = 0; n_ < 2; ++n_)                           \
        bF_[n_] = *(const bf16x8*)(Bp_ + n_ * 2048 + swz[ksv]);                \
    STAGE_STMT;                                                                \
    __builtin_amdgcn_s_barrier();                                              \
    __asm__ volatile("s_waitcnt lgkmcnt(0)" ::: "memory");                     \
    __builtin_amdgcn_s_setprio(1);                                             \
    _Pragma("unroll") for (int f_ = 0; f_ < 8; ++f_)                           \
        _Pragma("unroll") for (int n_ = 0; n_ < 2; ++n_)                       \
            acc[f_][n_] = MFMA16(aF_[f_], bF_[n_], acc[f_][n_]);               \
    __builtin_amdgcn_s_setprio(0);                                             \
    TAILWAIT;                                                                  \
    __builtin_amdgcn_s_barrier();                                              \
  } while (0)

__global__ __launch_bounds__(512, 2) void k_gemm_qkv(
    const __bf16* __restrict__ A, const __bf16* __restrict__ Bt,
    const float* __restrict__ bias,
    __bf16* __restrict__ Qg, __bf16* __restrict__ Kg, __bf16* __restrict__ VTg) {
  __shared__ __align__(16) char GS[147456];   // A 3x32K @0, B 3x16K @98304
  const int tid = threadIdx.x;
  const int w = tid >> 6, l = tid & 63;
  const int l15 = l & 15, quad = l >> 4;
  const int wr = w >> 2, wc = w & 3;          // 2M x 4N wave grid (128r x 32c each)

  // T1 bijective XCD swizzle: 768 blocks, 768 % 8 == 0. XCD c owns row-panels
  // by in [4c,4c+4), visited y-fastest within the chunk.
  const int Lid = blockIdx.x + 24 * blockIdx.y;
  const int xcd = Lid & 7;
  const int i96 = Lid >> 3;                   // [0,96)
  const int bx = i96 >> 2;                    // [0,24)
  const int by = (xcd << 2) + (i96 & 3);      // [0,32)
  const int bm0 = by * 256, bn0 = bx * 128;
  const int which = bx >> 3;                  // 0 Q, 1 K, 2 V (block-uniform)
  const float SC = 0.18033688011112042f;

  const int srow = tid >> 3;                  // [0,64) rows per 8KB call
  const int scol = ((tid & 7) ^ (srow & 7)) * 8;
  const __bf16* gA0 = A + (size_t)(bm0 + srow) * 1024 + scol;
  const __bf16* gB0 = Bt + (size_t)(bn0 + srow) * 1024 + scol;

  const int Abase = wr * 16384 + l15 * 128;   // wave's 128-row A span
  const int Bbase = wc * 4096 + l15 * 128;    // wave's 32-row B span
  int swz[2];
  swz[0] = ((0 + quad) ^ (l15 & 7)) * 16;
  swz[1] = ((4 + quad) ^ (l15 & 7)) * 16;

  f32x4 acc[8][2] = {};

  // prologue: stage tile0 -> buf0, tile1 -> buf1 (12 calls); wait 6 (tile0 done)
  STGA_CALL(0, 0, 0); STGA_CALL(0, 0, 1); STGA_CALL(0, 0, 2); STGA_CALL(0, 0, 3);
  STGB_CALL(0, 0, 0); STGB_CALL(0, 0, 1);
  STGA_CALL(1, 1, 0); STGA_CALL(1, 1, 1); STGA_CALL(1, 1, 2); STGA_CALL(1, 1, 3);
  STGB_CALL(1, 1, 0); STGB_CALL(1, 1, 1);
  WAITV6;
  __builtin_amdgcn_s_barrier();

  int b0 = 0;
#pragma unroll 1
  for (int u = 0; u < 16; ++u) {
    const int kt = (u + 2 < 16) ? u + 2 : 15;        // tail: redundant restage
    const int nb = (b0 + 2 >= 3) ? b0 - 1 : b0 + 2;  // (b0+2)%3
    PH2(0, b0, { STGA_CALL(kt, nb, 0); STGA_CALL(kt, nb, 1); STGB_CALL(kt, nb, 0); },
        NOWAIT);
    PH2(1, b0, { STGA_CALL(kt, nb, 2); STGA_CALL(kt, nb, 3); STGB_CALL(kt, nb, 1); },
        WAITV6);
    b0 = (b0 + 1 >= 3) ? 0 : b0 + 1;
  }

  __asm__ volatile("s_waitcnt vmcnt(0) lgkmcnt(0)" ::: "memory");
  __syncthreads();

  // per-wave output block: rows bm0 + wr*128 + f*16 + quad*4 + r (f=0..7),
  // cols bn0 + wc*32 + nf*16 + l15 (32-wide -> within ONE head).
  if (which < 2) {
    __bf16* dst = which == 0 ? Qg : Kg;
    const float mul = which == 0 ? SC : 1.0f;
    const int hh = ((bn0 + wc * 32) & 1023) >> 6;
    const int dc = (wc & 1) * 32;
    const int bb = bm0 >> 11;
    const int tt0 = (bm0 & 2047) + wr * 128;
    float bv2[2];
#pragma unroll
    for (int nf = 0; nf < 2; ++nf) bv2[nf] = bias[bn0 + wc * 32 + nf * 16 + l15];
    __bf16* TR = (__bf16*)(GS + w * 1600);   // 16 rows x 40 el (80B) per wave
    const int rr = l >> 2, cc = l & 3;
    __bf16* gbase = dst + ((size_t)(bb * 16 + hh) * 2048 + tt0) * 64 + dc;
#pragma unroll
    for (int f = 0; f < 8; ++f) {
#pragma unroll
      for (int nf = 0; nf < 2; ++nf)
#pragma unroll
        for (int r = 0; r < 4; ++r)
          TR[(quad * 4 + r) * 40 + nf * 16 + l15] =
              (__bf16)((acc[f][nf][r] + bv2[nf]) * mul);
      __asm__ volatile("s_waitcnt lgkmcnt(0)" ::: "memory");
      uint4 v0 = *(const uint4*)(TR + rr * 40 + cc * 8);
      __bf16* gp = gbase + (size_t)(f * 16 + rr) * 64 + cc * 8;
      *(uint4*)gp = v0;
      __asm__ volatile("" ::: "memory");  // keep TR reuse ordered across f
    }
  } else {
    const int v0n = bn0 + wc * 32 - 2048;
    const int hv = v0n >> 6;
    const int dc = v0n & 63;                 // = (wc&1)*32
    const int bb = bm0 >> 11;
    float bv2[2];
#pragma unroll
    for (int nf = 0; nf < 2; ++nf) bv2[nf] = bias[bn0 + wc * 32 + nf * 16 + l15];
    __bf16* VL = (__bf16*)(GS + w * 9216);   // 32 d x 136 t el per wave
    const int tloc = (bm0 & 2047) + wr * 128;
    __bf16* vrowb = VTg + ((size_t)(bb * 16 + hv) * 64 + dc) * 2048;
#pragma unroll
    for (int f = 0; f < 8; ++f)
#pragma unroll
      for (int nf = 0; nf < 2; ++nf)
#pragma unroll
        for (int r = 0; r < 4; ++r)
          VL[(nf * 16 + l15) * 136 + f * 16 + quad * 4 + r] =
              (__bf16)(acc[f][nf][r] + bv2[nf]);
    __asm__ volatile("s_waitcnt lgkmcnt(0)" ::: "memory");
    const int ch = l & 15;
#pragma unroll
    for (int it = 0; it < 8; ++it) {
      const int dr = 4 * it + (l >> 4);
      uint4 vv = *(const uint4*)(VL + dr * 136 + ch * 8);
      *(uint4*)(vrowb + (size_t)dr * 2048 + tloc + ch * 8) = vv;
    }
  }
}

// ---------------- Flash attention: 8 waves, split-kv, 32x32 MFMA ----------------
// R0/R1-exact structure (best measured: 64.4 us; NO setprio -- R6 A/B showed
// setprio costs +8.5 us in this lockstep-barrier structure, cf. m190).
// Grid (64, 8), 512 threads. Block handles q-tiles {p, 15-p} -> every block
// has EQUAL total work (17 j-iters); 2 blocks/CU (66.5 KiB LDS).
__global__ __launch_bounds__(512) void k_attn(
    const __bf16* __restrict__ Qg, const __bf16* __restrict__ Kg,
    const __bf16* __restrict__ VTg, __bf16* __restrict__ yb) {
  __shared__ __align__(16) char smem[66560];
  const int tid = threadIdx.x;
  const int w = tid >> 6, l = tid & 63;
  const int wq = w & 3, hf = w >> 2, wqh = wq >> 1;
  const int l31 = l & 31, cH = l >> 5;
  const int bh = blockIdx.x;
  const int bb = bh >> 4, h = bh & 15;
  const __bf16* Qb = Qg + (size_t)bh * 2048 * 64;

  // staging addresses
  const int rk = w * 8 + (l >> 3);
  const __bf16* gK = Kg + ((size_t)bh * 2048 + rk) * 64 + (((l & 7) ^ (rk & 7)) * 8);
  const int rv = w * 4 + (l >> 4);
  const int rvB = rv + 32;
  const __bf16* gVA = VTg + ((size_t)bh * 64 + rv) * 2048 +
                      (((l & 8) | ((l & 7) ^ (rv & 7))) * 8);
  const __bf16* gVB = VTg + ((size_t)bh * 64 + rvB) * 2048 +
                      (((l & 8) | ((l & 7) ^ (rvB & 7))) * 8);

  // lane-constant LDS read offsets (bytes), hoisted out of the k-loop
  const int R0 = 64 * hf + l31;
  int koff[4], koff1[4];
#pragma unroll
  for (int s = 0; s < 4; ++s) {
    koff[s]  = R0 * 64 * 2 + (((2 * s + cH) ^ (R0 & 7)) * 16);
    koff1[s] = (R0 + 32) * 64 * 2 + (((2 * s + cH) ^ (R0 & 7)) * 16);
  }
#if HAVE_MFMA8
  int voff[2][4], voff1[2][4];
#pragma unroll
  for (int kvt = 0; kvt < 2; ++kvt)
#pragma unroll
    for (int g = 0; g < 4; ++g) {
      const int slot = (8 * hf) | ((4 * kvt + g) ^ (l31 & 7));
      voff[kvt][g]  = l31 * 256 + slot * 16 + 8 * cH;
      voff1[kvt][g] = (32 + l31) * 256 + slot * 16 + 8 * cH;
    }
#else
  int voffL[4], voffL1[4];
#pragma unroll
  for (int s = 0; s < 4; ++s) {
    const int sl0 = (8 * hf) | ((2 * s + cH) ^ (l31 & 7));
    voffL[s]  = l31 * 256 + sl0 * 16;
    voffL1[s] = (32 + l31) * 256 + sl0 * 16;
  }
#endif

  for (int seg = 0; seg < 2; ++seg) {
    const int p = seg ? 15 - blockIdx.y : blockIdx.y;
    const int qt0 = p * 128 + wq * 32;
    const int q = qt0 + l31;

    __syncthreads();

    bf16x8 qf[4];
#pragma unroll
    for (int s = 0; s < 4; ++s)
      qf[s] = *(const bf16x8*)(Qb + (size_t)q * 64 + s * 16 + cH * 8);

    f32x16 o0 = {}, o1 = {};
    float lsum = 0.f;

    {
      char* KSb = smem;
      char* VSb = smem + 32768;
      gload_lds16(gK,           KSb + w * 1024);
      gload_lds16(gK + 64 * 64, KSb + 8192 + w * 1024);
      gload_lds16(gVA,          VSb + w * 1024);
      gload_lds16(gVB,          VSb + 8192 + w * 1024);
    }

    for (int j = 0; j <= p; ++j) {
      __syncthreads();
      if (j < p) {
        const int b2 = (j + 1) & 1;
        char* KSb = smem + b2 * 16384;
        char* VSb = smem + 32768 + b2 * 16384;
        const size_t ko = (size_t)(128 * (j + 1)) * 64;
        gload_lds16(gK + ko,             KSb + w * 1024);
        gload_lds16(gK + ko + 64 * 64,   KSb + 8192 + w * 1024);
        gload_lds16(gVA + 128 * (j + 1), VSb + w * 1024);
        gload_lds16(gVB + 128 * (j + 1), VSb + 8192 + w * 1024);
      }
      const bool act = (j < p) || (hf <= wqh);
      if (act) {
        const bool diag = (j == p) && (hf == wqh);
        const char* KSb = smem + (j & 1) * 16384;
        const char* VSb = smem + 32768 + (j & 1) * 16384;
        const int kv0 = (2 * j + hf) * 64;

        bf16x8 kf0[4], kf1[4];
#pragma unroll
        for (int s = 0; s < 4; ++s) {
          kf0[s] = *(const bf16x8*)(KSb + koff[s]);
          kf1[s] = *(const bf16x8*)(KSb + koff1[s]);
        }
        f32x16 st0 = {}, st1 = {};
#pragma unroll
        for (int s = 0; s < 4; ++s) st0 = MFMA32(kf0[s], qf[s], st0);
#pragma unroll
        for (int s = 0; s < 4; ++s) st1 = MFMA32(kf1[s], qf[s], st1);

        if (diag) {
          const int base0 = kv0 + 4 * cH;
          const int base1 = kv0 + 32 + 4 * cH;
#pragma unroll
          for (int r = 0; r < 16; ++r) {
            const int off = (r & 3) + 8 * (r >> 2);
            if (base0 + off > q) st0[r] = -1e30f;
            if (base1 + off > q) st1[r] = -1e30f;
          }
        }

        // exp2 (fixed max 0), pairwise-tree sum, pack to bf16 dwords
        uint32_t pk[2][4][2];
        float sacc[2];
#pragma unroll
        for (int kvt = 0; kvt < 2; ++kvt) {
          float pp[16];
#pragma unroll
          for (int r = 0; r < 16; ++r) pp[r] = fexp2(kvt ? st1[r] : st0[r]);
          float s01 = (pp[0] + pp[1]) + (pp[2] + pp[3]);
          float s23 = (pp[4] + pp[5]) + (pp[6] + pp[7]);
          float s45 = (pp[8] + pp[9]) + (pp[10] + pp[11]);
          float s67 = (pp[12] + pp[13]) + (pp[14] + pp[15]);
          sacc[kvt] = (s01 + s23) + (s45 + s67);
#pragma unroll
          for (int rq = 0; rq < 4; ++rq) {
            pk[kvt][rq][0] = pack_bf16(pp[4 * rq], pp[4 * rq + 1]);
            pk[kvt][rq][1] = pack_bf16(pp[4 * rq + 2], pp[4 * rq + 3]);
          }
        }
        lsum += sacc[0] + sacc[1];

#if HAVE_MFMA8
        // PV: K=8 MFMA, pk dwords are the B-fragment directly (no shuffles)
#pragma unroll
        for (int kvt = 0; kvt < 2; ++kvt)
#pragma unroll
          for (int g = 0; g < 4; ++g) {
            const uint2 va = *(const uint2*)(VSb + voff[kvt][g]);
            const uint2 vb = *(const uint2*)(VSb + voff1[kvt][g]);
            o0 = MFMA8(va.x, va.y, pk[kvt][g][0], pk[kvt][g][1], o0);
            o1 = MFMA8(vb.x, vb.y, pk[kvt][g][0], pk[kvt][g][1], o1);
          }
#else
        // fallback: K=16 MFMA with bpermute-based B-fragment assembly
        bf16x8 vf0[4], vf1[4];
#pragma unroll
        for (int s = 0; s < 4; ++s) {
          vf0[s] = *(const bf16x8*)(VSb + voffL[s]);
          vf1[s] = *(const bf16x8*)(VSb + voffL1[s]);
        }
#pragma unroll
        for (int s = 0; s < 4; ++s) {
          const int kvt = s >> 1;
          const int rq_own = 2 * (s & 1) + cH;
          const int rq_snd = 2 * (s & 1) + 1 - cH;
          const uint32_t own0 = pk[kvt][rq_own][0], own1 = pk[kvt][rq_own][1];
          const uint32_t rcv0 = (uint32_t)__shfl_xor((int)pk[kvt][rq_snd][0], 32, 64);
          const uint32_t rcv1 = (uint32_t)__shfl_xor((int)pk[kvt][rq_snd][1], 32, 64);
          union { uint32_t u[4]; bf16x8 v; } pf;
          pf.u[0] = cH ? rcv0 : own0;
          pf.u[1] = cH ? rcv1 : own1;
          pf.u[2] = cH ? own0 : rcv0;
          pf.u[3] = cH ? own1 : rcv1;
          o0 = MFMA32(vf0[s], pf.v, o0);
          o1 = MFMA32(vf1[s], pf.v, o1);
        }
#endif
      }
    }

    // split-kv merge: half1 writes (o, sum) to LDS; half0 combines and stores y
    __syncthreads();
    float4* Msh = (float4*)smem;
    float* Ls2 = (float*)(smem + 65536);
    const float stot = lsum + __shfl_xor(lsum, 32, 64);
    union { f32x16 v; float4 q4[4]; } u0, u1;
    u0.v = o0; u1.v = o1;
    if (hf == 1) {
#pragma unroll
      for (int i = 0; i < 4; ++i) {
        Msh[(i * 4 + wq) * 64 + l] = u0.q4[i];
        Msh[((i + 4) * 4 + wq) * 64 + l] = u1.q4[i];
      }
      Ls2[wq * 64 + l] = stot;
    }
    __syncthreads();
    if (hf == 0) {
#pragma unroll
      for (int i = 0; i < 4; ++i) {
        float4 a = Msh[(i * 4 + wq) * 64 + l];
        float4 b2 = Msh[((i + 4) * 4 + wq) * 64 + l];
        u0.q4[i].x += a.x; u0.q4[i].y += a.y; u0.q4[i].z += a.z; u0.q4[i].w += a.w;
        u1.q4[i].x += b2.x; u1.q4[i].y += b2.y; u1.q4[i].z += b2.z; u1.q4[i].w += b2.w;
      }
      const float inv = 1.0f / (stot + Ls2[wq * 64 + l]);
      __bf16* yrow = yb + ((size_t)(bb * 2048 + q)) * 1024 + h * 64;
#pragma unroll
      for (int dt = 0; dt < 2; ++dt) {
        const f32x16& o = dt ? u1.v : u0.v;
#pragma unroll
        for (int rq = 0; rq < 4; ++rq) {
          __bf16 ov[4];
#pragma unroll
          for (int i = 0; i < 4; ++i) ov[i] = (__bf16)(o[4 * rq + i] * inv);
          *(uint2*)(yrow + dt * 32 + 8 * rq + 4 * cH) = *(uint2*)ov;
        }
      }
    }
  }
}

// ---------------- GEMM2: out = y @ W_proj + b_proj (fp32 out) ----------------
// 2-phase LDS double-buffer + conflict-free swizzled reads (T2) + XCD swizzle (T1).
__global__ __launch_bounds__(256) void k_gemm_proj(
    const __bf16* __restrict__ A, const __bf16* __restrict__ Bt,
    const float* __restrict__ bias, float* __restrict__ out) {
  __shared__ __align__(16) __bf16 As[2][128 * 32];
  __shared__ __align__(16) __bf16 Bs[2][128 * 32];
  const int tid = threadIdx.x;
  const int w = tid >> 6, l = tid & 63;
  const int l15 = l & 15, quad = l >> 4;
  const int wr = w >> 1, wc = w & 1;

  const int Lid = blockIdx.x + 8 * blockIdx.y;    // 512 blocks, 512 % 8 == 0
  const int xcd = Lid & 7;
  const int i64 = Lid >> 3;                       // [0,64)
  const int bx = i64 >> 3;                        // [0,8)
  const int by = (xcd << 3) + (i64 & 7);          // [0,64)
  const int bm0 = by * 128, bn0 = bx * 128;

  const int rs = w * 32 + (l >> 2);
  const int kc = ((l & 3) ^ ((l >> 3) & 3)) * 8;
  const __bf16* gA = A + (size_t)(bm0 + rs) * 1024 + kc;
  const __bf16* gB = Bt + (size_t)(bn0 + rs) * 1024 + kc;
  const int sq = (quad ^ ((l15 >> 1) & 3)) * 8;

  f32x4 acc[4][4] = {};

  gload_lds16(gA,             As[0] + w * 1024);
  gload_lds16(gA + 16 * 1024, As[0] + w * 1024 + 512);
  gload_lds16(gB,             Bs[0] + w * 1024);
  gload_lds16(gB + 16 * 1024, Bs[0] + w * 1024 + 512);
  __syncthreads();

  int buf = 0;
  for (int k0 = 0; k0 < 1024; k0 += 32) {
    if (k0 < 992) {
      const int nb = buf ^ 1;
      gload_lds16(gA + k0 + 32,             As[nb] + w * 1024);
      gload_lds16(gA + k0 + 32 + 16 * 1024, As[nb] + w * 1024 + 512);
      gload_lds16(gB + k0 + 32,             Bs[nb] + w * 1024);
      gload_lds16(gB + k0 + 32 + 16 * 1024, Bs[nb] + w * 1024 + 512);
    }
    bf16x8 af[4], bv[4];
#pragma unroll
    for (int mt = 0; mt < 4; ++mt)
      af[mt] = *(const bf16x8*)(As[buf] + (wr * 64 + mt * 16 + l15) * 32 + sq);
#pragma unroll
    for (int nt = 0; nt < 4; ++nt)
      bv[nt] = *(const bf16x8*)(Bs[buf] + (wc * 64 + nt * 16 + l15) * 32 + sq);
#pragma unroll
    for (int mt = 0; mt < 4; ++mt)
#pragma unroll
      for (int nt = 0; nt < 4; ++nt)
        acc[mt][nt] = MFMA16(af[mt], bv[nt], acc[mt][nt]);
    __syncthreads();
    buf ^= 1;
  }

#pragma unroll
  for (int nt = 0; nt < 4; ++nt) {
    const int n = bn0 + wc * 64 + nt * 16 + l15;
    const float bvv = bias[n];
#pragma unroll
    for (int mt = 0; mt < 4; ++mt) {
#pragma unroll
      for (int r = 0; r < 4; ++r) {
        const int m = bm0 + wr * 64 + mt * 16 + quad * 4 + r;
        out[(size_t)m * 1024 + n] = acc[mt][nt][r] + bvv;
      }
    }
  }
}

extern "C" void kernel_launch(void* const* d_in, const int* in_sizes, int n_in,
                              void* d_out, int out_size, void* d_ws, size_t ws_size,
                              hipStream_t stream) {
  const float* x      = (const float*)d_in[0];
  const float* W_attn = (const float*)d_in[1];
  const float* b_attn = (const float*)d_in[2];
  const float* W_proj = (const float*)d_in[3];
  const float* b_proj = (const float*)d_in[4];
  float* out = (float*)d_out;
  char* ws = (char*)d_ws;

  __bf16* xb  = (__bf16*)(ws);                     // 16 MiB  x bf16; later reused as y
  __bf16* WaT = (__bf16*)(ws + (16ull << 20));     //  6 MiB  W_attn^T bf16
  __bf16* WpT = (__bf16*)(ws + (22ull << 20));     //  2 MiB  W_proj^T bf16
  __bf16* Qg  = (__bf16*)(ws + (24ull << 20));     // 16 MiB  Q*SC [bh][T][64]
  __bf16* Kg  = (__bf16*)(ws + (40ull << 20));     // 16 MiB  K [bh][T][64]
  __bf16* VTg = (__bf16*)(ws + (56ull << 20));     // 16 MiB  V^T [bh][64][T]

  k_cvt<<<8192, 256, 0, stream>>>(x, xb, 2097152);
  k_transpose<<<dim3(96, 32), 256, 0, stream>>>(W_attn, WaT, 1024, 3072);
  k_transpose<<<dim3(32, 32), 256, 0, stream>>>(W_proj, WpT, 1024, 1024);
  k_gemm_qkv<<<dim3(24, 32), 512, 0, stream>>>(xb, WaT, b_attn, Qg, Kg, VTg);
  k_attn<<<dim3(64, 8), 512, 0, stream>>>(Qg, Kg, VTg, xb /* y reuses xb */);
  k_gemm_proj<<<dim3(8, 64), 256, 0, stream>>>(xb, WpT, b_proj, out);
}